// Round 4
// baseline (110.863 us; speedup 1.0000x reference)
//
#include <hip/hip_runtime.h>

#define BB 16
#define NN 300
#define PP 100
#define LL 32
#define HH 768
#define WW 768
#define TSS 32                 // rows per strip
#define NSTRIP 24              // 24*32 = 768
#define KCOLS 32               // columns per block (32*4B = 128B = full L2 line)
#define NGRP (WW / KCOLS)      // 24 column-groups
#define NEV (2 * NN)
#define NDETBLK 19             // ceil(4800/256)

__device__ __forceinline__ float relu_f(float x) { return fmaxf(x, 0.f); }

// ---------------------------------------------------------------------------
// K1 (fused): per-column vertical running prefix of d = seg[2]-seg[1], with
// box-sums accumulated on the fly at event rows (y2-1: +, y1-1: -).
// Block = NSTRIP x KCOLS = 768 threads; grid = BB * NGRP = 384.
// No prefix image is materialized; HBM traffic = the 75.5 MB input read.
// ---------------------------------------------------------------------------
__global__ __launch_bounds__(768) void k_fused(const float* __restrict__ seg,
                                               const float* __restrict__ det_boxes,
                                               const float* __restrict__ logits,
                                               float* __restrict__ detPartial) {
    const int blk = blockIdx.x;
    const int b   = blk / NGRP;
    const int g   = blk % NGRP;
    const int x0  = g * KCOLS;
    const int t   = threadIdx.x;
    const int c   = t & 31;            // column within group
    const int s   = t >> 5;            // strip 0..23
    const int x   = x0 + c;
    const int y0  = s * TSS;

    __shared__ int   bx1[NN], bx2[NN];
    __shared__ int   rowOff[HH + 1];
    __shared__ int   rowCnt[HH];       // counts, then reused as scatter cursor
    __shared__ int   events[NEV];      // (box<<1) | is_minus
    __shared__ float boxAcc[NN];
    __shared__ float S[NSTRIP][KCOLS];

    for (int y = t; y < HH; y += 768) rowCnt[y] = 0;
    for (int j = t; j < NN; j += 768) boxAcc[j] = 0.f;
    __syncthreads();

    // --- box metadata: each thread owns <=1 box -----------------------------
    int  my_y1 = 0, my_y2 = 0;
    bool my_valid = false;
    if (t < NN) {
        const float* lg = logits + ((size_t)b * NN + t) * 7;
        float m = lg[0];
        #pragma unroll
        for (int i = 1; i < 7; ++i) m = fmaxf(m, lg[i]);
        float sum = 0.f;
        #pragma unroll
        for (int i = 0; i < 7; ++i) sum += expf(lg[i] - m);
        float conf = 1.f / sum;

        const float* bxp = det_boxes + ((size_t)b * NN + t) * 4;
        float cx = bxp[0], cy = bxp[1], w = bxp[2], h = bxp[3];
        int xx1 = (int)floorf((cx - w * 0.5f) * (float)WW);
        int yy1 = (int)floorf((cy - h * 0.5f) * (float)HH);
        int xx2 = (int)floorf((cx + w * 0.5f) * (float)WW);
        int yy2 = (int)floorf((cy + h * 0.5f) * (float)HH);
        xx1 = min(max(xx1, 0), WW - 1); yy1 = min(max(yy1, 0), HH - 1);
        xx2 = min(max(xx2, 0), WW - 1); yy2 = min(max(yy2, 0), HH - 1);
        my_valid = (conf >= 0.3f) && (xx2 > xx1) && (yy2 > yy1);
        bx1[t] = my_valid ? xx1 : 0;
        bx2[t] = my_valid ? xx2 : 0;   // empty range when invalid
        my_y1 = yy1; my_y2 = yy2;
        if (my_valid) {
            atomicAdd(&rowCnt[yy2 - 1], 1);
            if (yy1 > 0) atomicAdd(&rowCnt[yy1 - 1], 1);
        }
    }
    __syncthreads();

    // --- exclusive scan of rowCnt -> rowOff (single wave) -------------------
    if (t < 64) {
        int base = t * 12;             // 64*12 = 768 rows
        int local[12]; int run = 0;
        #pragma unroll
        for (int k = 0; k < 12; ++k) { local[k] = run; run += rowCnt[base + k]; }
        int inc = run;
        #pragma unroll
        for (int d = 1; d < 64; d <<= 1) {
            int o = __shfl_up(inc, d, 64);
            if (t >= d) inc += o;
        }
        int excl = inc - run;
        #pragma unroll
        for (int k = 0; k < 12; ++k) rowOff[base + k] = excl + local[k];
        if (t == 63) rowOff[HH] = inc;
    }
    __syncthreads();
    for (int y = t; y < HH; y += 768) rowCnt[y] = rowOff[y];   // cursor
    __syncthreads();
    if (t < NN && my_valid) {
        int slot = atomicAdd(&rowCnt[my_y2 - 1], 1);
        events[slot] = (t << 1);
        if (my_y1 > 0) {
            slot = atomicAdd(&rowCnt[my_y1 - 1], 1);
            events[slot] = (t << 1) | 1;
        }
    }
    __syncthreads();

    // --- pass 1: strip-local prefix walk, event accumulation ----------------
    const float* p1 = seg + ((size_t)(b * 3 + 1) * HH + y0) * WW + x;
    const float* p2 = seg + ((size_t)(b * 3 + 2) * HH + y0) * WW + x;
    float acc = 0.f;
    #pragma unroll 4
    for (int i = 0; i < TSS; ++i) {
        acc += p2[(size_t)i * WW] - p1[(size_t)i * WW];
        const int y = y0 + i;
        const int e1 = rowOff[y + 1];
        for (int e = rowOff[y]; e < e1; ++e) {
            int pk = events[e]; int j = pk >> 1;
            float v = (x >= bx1[j] && x < bx2[j]) ? acc : 0.f;
            #pragma unroll
            for (int mm = 16; mm; mm >>= 1) v += __shfl_xor(v, mm, 32);
            if (c == 0) atomicAdd(&boxAcc[j], (pk & 1) ? -v : v);
        }
    }
    S[s][c] = acc;
    __syncthreads();

    // --- strip carry + carry sweep over this strip's events -----------------
    float carry = 0.f;
    for (int sp = 0; sp < s; ++sp) carry += S[sp][c];
    const int e1c = rowOff[y0 + TSS];
    for (int e = rowOff[y0]; e < e1c; ++e) {
        int pk = events[e]; int j = pk >> 1;
        float v = (x >= bx1[j] && x < bx2[j]) ? carry : 0.f;
        #pragma unroll
        for (int mm = 16; mm; mm >>= 1) v += __shfl_xor(v, mm, 32);
        if (c == 0) atomicAdd(&boxAcc[j], (pk & 1) ? -v : v);
    }
    __syncthreads();

    for (int j = t; j < NN; j += 768)
        detPartial[((size_t)b * NN + j) * NGRP + g] = boxAcc[j];
}

// ---------------------------------------------------------------------------
// K2: blocks 0..18 finalize det term (sum 24 partials in fixed order);
//     blocks 19..34 do plate IoU + OCR for batch b = blk-19.
// ---------------------------------------------------------------------------
__global__ __launch_bounds__(256) void k_small(const float* __restrict__ det_boxes,
                                               const float* __restrict__ logits,
                                               const float* __restrict__ plate_boxes,
                                               const float* __restrict__ plate_conf,
                                               const float* __restrict__ ocr,
                                               const float* __restrict__ detPartial,
                                               float* __restrict__ detPart,
                                               float* __restrict__ platePart,
                                               float* __restrict__ plateCnt,
                                               float* __restrict__ ocrPart) {
    const int t = threadIdx.x;
    if (blockIdx.x < NDETBLK) {
        const int idx = blockIdx.x * 256 + t;
        float contrib = 0.f;
        if (idx < BB * NN) {
            const float* lg = logits + (size_t)idx * 7;
            float m = lg[0];
            #pragma unroll
            for (int i = 1; i < 7; ++i) m = fmaxf(m, lg[i]);
            float ssum = 0.f;
            #pragma unroll
            for (int i = 0; i < 7; ++i) ssum += expf(lg[i] - m);
            float conf = 1.f / ssum;

            const float* bxp = det_boxes + (size_t)idx * 4;
            float cx = bxp[0], cy = bxp[1], w = bxp[2], h = bxp[3];
            int x1 = (int)floorf((cx - w * 0.5f) * (float)WW);
            int y1 = (int)floorf((cy - h * 0.5f) * (float)HH);
            int x2 = (int)floorf((cx + w * 0.5f) * (float)WW);
            int y2 = (int)floorf((cy + h * 0.5f) * (float)HH);
            x1 = min(max(x1, 0), WW - 1); y1 = min(max(y1, 0), HH - 1);
            x2 = min(max(x2, 0), WW - 1); y2 = min(max(y2, 0), HH - 1);
            if (conf >= 0.3f && x2 > x1 && y2 > y1) {
                const float* pp = detPartial + (size_t)idx * NGRP;
                float Sb = 0.f;
                #pragma unroll
                for (int g2 = 0; g2 < NGRP; ++g2) Sb += pp[g2];
                float area = (float)((y2 - y1) * (x2 - x1));
                contrib = relu_f(Sb / area) * conf;
            }
        }
        __shared__ float red[256];
        red[t] = contrib;
        __syncthreads();
        for (int k = 128; k > 0; k >>= 1) {
            if (t < k) red[t] += red[t + k];
            __syncthreads();
        }
        if (t == 0) detPart[blockIdx.x] = red[0];
    } else {
        const float CONF_TH = 0.3f, MIN_IOU = 0.5f, OCR_TH = 0.7f;
        const int b = blockIdx.x - NDETBLK;

        __shared__ float vx1[NN], vy1[NN], vx2[NN], vy2[NN], va[NN], vcf[NN];
        __shared__ int anyv;
        __shared__ float redf[256];
        __shared__ int   redi[256];

        if (t == 0) anyv = 0;
        __syncthreads();

        for (int j = t; j < NN; j += 256) {
            const float* bxp = det_boxes + ((size_t)b * NN + j) * 4;
            float cx = bxp[0], cy = bxp[1], w = bxp[2], h = bxp[3];
            float x1 = cx - w * 0.5f, y1 = cy - h * 0.5f;
            float x2 = cx + w * 0.5f, y2 = cy + h * 0.5f;
            vx1[j] = x1; vy1[j] = y1; vx2[j] = x2; vy2[j] = y2;
            va[j] = (x2 - x1) * (y2 - y1);
            const float* lg = logits + ((size_t)b * NN + j) * 7;
            float m = lg[0];
            #pragma unroll
            for (int i = 1; i < 7; ++i) m = fmaxf(m, lg[i]);
            float sum = 0.f;
            #pragma unroll
            for (int i = 0; i < 7; ++i) sum += expf(lg[i] - m);
            float cc = 1.f / sum;
            vcf[j] = cc;
            if (cc > CONF_TH) atomicOr(&anyv, 1);
        }
        __syncthreads();

        float term = 0.f; int pv = 0; float pcf = -1e30f;
        if (t < PP) {
            const float* bxp = plate_boxes + ((size_t)b * PP + t) * 4;
            float cx = bxp[0], cy = bxp[1], w = bxp[2], h = bxp[3];
            float px1 = cx - w * 0.5f, py1 = cy - h * 0.5f;
            float px2 = cx + w * 0.5f, py2 = cy + h * 0.5f;
            float a1 = (px2 - px1) * (py2 - py1);
            pcf = plate_conf[b * PP + t];
            pv = (pcf > CONF_TH) ? 1 : 0;
            float max_iou = -1.f;
            for (int j = 0; j < NN; ++j) {
                if (vcf[j] > CONF_TH) {
                    float ltx = fmaxf(px1, vx1[j]);
                    float lty = fmaxf(py1, vy1[j]);
                    float rbx = fminf(px2, vx2[j]);
                    float rby = fminf(py2, vy2[j]);
                    float iw = fmaxf(rbx - ltx, 0.f);
                    float ih = fmaxf(rby - lty, 0.f);
                    float inter = iw * ih;
                    float uni = a1 + va[j] - inter;
                    float iou = inter / (uni + 1e-8f);
                    max_iou = fmaxf(max_iou, iou);
                }
            }
            if (pv) term = relu_f(MIN_IOU - max_iou) * pcf;
        }

        redf[t] = term; redi[t] = pv;
        __syncthreads();
        for (int k = 128; k > 0; k >>= 1) {
            if (t < k) { redf[t] += redf[t + k]; redi[t] += redi[t + k]; }
            __syncthreads();
        }
        float termsum = redf[0];
        int   cnt     = redi[0];
        __syncthreads();

        float osum = 0.f;
        if (t < LL) {
            const float* op = ocr + ((size_t)b * LL + t) * 37;
            float m = op[0];
            #pragma unroll
            for (int i = 1; i < 37; ++i) m = fmaxf(m, op[i]);
            osum = m;
        }
        redf[t] = osum;
        __syncthreads();
        for (int k = 128; k > 0; k >>= 1) {
            if (t < k) redf[t] += redf[t + k];
            __syncthreads();
        }
        float avg_ocr = redf[0] / (float)LL;
        __syncthreads();

        redf[t] = (t < PP) ? pcf : -1e30f;
        __syncthreads();
        for (int k = 128; k > 0; k >>= 1) {
            if (t < k) redf[t] = fmaxf(redf[t], redf[t + k]);
            __syncthreads();
        }
        float max_plate = redf[0];

        if (t == 0) {
            platePart[b] = (cnt > 0 && anyv) ? termsum : 0.f;
            plateCnt[b]  = (float)cnt;
            ocrPart[b]   = (avg_ocr > OCR_TH) ? relu_f(avg_ocr - max_plate) : 0.f;
        }
    }
}

// ---------------------------------------------------------------------------
// K3: final deterministic combine.
// ---------------------------------------------------------------------------
__global__ __launch_bounds__(64) void k_final(const float* __restrict__ detPart,
                                              const float* __restrict__ platePart,
                                              const float* __restrict__ plateCnt,
                                              const float* __restrict__ ocrPart,
                                              float* __restrict__ out) {
    if (threadIdx.x == 0 && blockIdx.x == 0) {
        double ds = 0.0;
        for (int i = 0; i < NDETBLK; ++i) ds += (double)detPart[i];
        double ps = 0.0, cnt = 0.0, os = 0.0;
        for (int b = 0; b < BB; ++b) {
            ps  += (double)platePart[b];
            cnt += (double)plateCnt[b];
            os  += (double)ocrPart[b];
        }
        float det_seg   = (float)ds / (float)(BB * NN);
        float plate_det = (float)ps / fmaxf((float)cnt, 1.f);
        float ocr_plate = (float)os / (float)BB;
        out[0] = 0.1f * det_seg + 0.1f * plate_det + 0.1f * ocr_plate;
    }
}

extern "C" void kernel_launch(void* const* d_in, const int* in_sizes, int n_in,
                              void* d_out, int out_size, void* d_ws, size_t ws_size,
                              hipStream_t stream) {
    const float* det_boxes   = (const float*)d_in[0];
    const float* det_logits  = (const float*)d_in[1];
    const float* seg_masks   = (const float*)d_in[2];
    const float* plate_boxes = (const float*)d_in[3];
    const float* plate_conf  = (const float*)d_in[4];
    const float* ocr_probs   = (const float*)d_in[5];
    float* out = (float*)d_out;

    // workspace layout (floats)
    float* detPartial = (float*)d_ws;                        // B*N*NGRP = 115200
    float* detPart    = detPartial + (size_t)BB * NN * NGRP; // 19
    float* platePart  = detPart + NDETBLK;                   // 16
    float* plateCnt   = platePart + BB;                      // 16
    float* ocrPart    = plateCnt + BB;                       // 16

    k_fused<<<BB * NGRP, NSTRIP * KCOLS, 0, stream>>>(seg_masks, det_boxes,
                                                      det_logits, detPartial);
    k_small<<<NDETBLK + BB, 256, 0, stream>>>(det_boxes, det_logits, plate_boxes,
                                              plate_conf, ocr_probs, detPartial,
                                              detPart, platePart, plateCnt, ocrPart);
    k_final<<<1, 64, 0, stream>>>(detPart, platePart, plateCnt, ocrPart, out);
}

// Round 5
// 62.838 us; speedup vs baseline: 1.7643x; 1.7643x over previous
//
#include <hip/hip_runtime.h>

#define BB 16
#define NN 300
#define PP 100
#define LL 32
#define HH 768
#define WW 768
#define BAND 16                 // rows per band-block
#define NBAND (HH / BAND)       // 48
#define PSTR 772                // LDS row stride in floats (16B-aligned, bank-skewed)
#define NDETBLK 19              // ceil(4800/256)

__device__ __forceinline__ float relu_f(float x) { return fmaxf(x, 0.f); }

// ---------------------------------------------------------------------------
// K1: one block per (batch, 16-row band). Phase A: row prefix sums of
// d = seg[2]-seg[1] into LDS via float4 streaming loads + wave shuffle scan.
// Phase B: one thread per box accumulates P[r][x2-1]-P[r][x1-1] over the
// band's rows. Phase C: contiguous 300-float partial write. No atomics.
// Grid: 768 blocks of 512 threads; LDS 51.8 KB -> 3 blocks/CU, 24 waves/CU.
// ---------------------------------------------------------------------------
__global__ __launch_bounds__(512) void k_band(const float* __restrict__ seg,
                                              const float* __restrict__ det_boxes,
                                              const float* __restrict__ logits,
                                              float* __restrict__ detPartial) {
    const int blk  = blockIdx.x;
    const int b    = blk / NBAND;
    const int band = blk % NBAND;
    const int y0   = band * BAND;
    const int t    = threadIdx.x;
    const int wave = t >> 6, lane = t & 63;

    __shared__ float P[BAND * PSTR];   // 49408 B
    __shared__ int metaX[NN];          // x1 | ((x2-1) << 16), 0 if invalid
    __shared__ int metaY[NN];          // y1 | (y2 << 16),     0 if invalid

    // ---- Phase 0: box metadata (each thread <=1 box) -----------------------
    for (int j = t; j < NN; j += 512) {
        const float* lg = logits + ((size_t)b * NN + j) * 7;
        float m = lg[0];
        #pragma unroll
        for (int i = 1; i < 7; ++i) m = fmaxf(m, lg[i]);
        float sum = 0.f;
        #pragma unroll
        for (int i = 0; i < 7; ++i) sum += expf(lg[i] - m);
        float conf = 1.f / sum;

        const float* bxp = det_boxes + ((size_t)b * NN + j) * 4;
        float cx = bxp[0], cy = bxp[1], w = bxp[2], h = bxp[3];
        int x1 = (int)floorf((cx - w * 0.5f) * (float)WW);
        int y1 = (int)floorf((cy - h * 0.5f) * (float)HH);
        int x2 = (int)floorf((cx + w * 0.5f) * (float)WW);
        int y2 = (int)floorf((cy + h * 0.5f) * (float)HH);
        x1 = min(max(x1, 0), WW - 1); y1 = min(max(y1, 0), HH - 1);
        x2 = min(max(x2, 0), WW - 1); y2 = min(max(y2, 0), HH - 1);
        bool valid = (conf >= 0.3f) && (x2 > x1) && (y2 > y1);
        metaX[j] = valid ? (x1 | ((x2 - 1) << 16)) : 0;
        metaY[j] = valid ? (y1 | (y2 << 16)) : 0;   // empty y-range if invalid
    }

    // ---- Phase A: 8 waves x 2 rows, float4 stream + shuffle scan -----------
    const float4* r1base = (const float4*)(seg + (size_t)(b * 3 + 1) * HH * WW);
    const float4* r2base = (const float4*)(seg + (size_t)(b * 3 + 2) * HH * WW);
    #pragma unroll
    for (int rr = 0; rr < 2; ++rr) {
        const int r = wave * 2 + rr;
        const int y = y0 + r;
        const float4* q1 = r1base + (size_t)y * (WW / 4);
        const float4* q2 = r2base + (size_t)y * (WW / 4);
        float* Prow = P + r * PSTR;
        float carry = 0.f;
        #pragma unroll
        for (int c = 0; c < 3; ++c) {
            float4 a = q1[c * 64 + lane];
            float4 o = q2[c * 64 + lane];
            float dx = o.x - a.x, dy = o.y - a.y, dz = o.z - a.z, dw = o.w - a.w;
            float s = dx + dy + dz + dw;
            float incl = s;
            #pragma unroll
            for (int d = 1; d < 64; d <<= 1) {
                float u = __shfl_up(incl, d, 64);
                if (lane >= d) incl += u;
            }
            float base = carry + incl - s;
            float4 pv;
            pv.x = base + dx; pv.y = pv.x + dy; pv.z = pv.y + dz; pv.w = pv.z + dw;
            *(float4*)(Prow + c * 256 + lane * 4) = pv;
            carry += __shfl(incl, 63, 64);
        }
    }
    __syncthreads();

    // ---- Phase B+C: per-box accumulation over band rows, contiguous write --
    float* outp = detPartial + ((size_t)b * NBAND + band) * NN;
    for (int j = t; j < NN; j += 512) {
        int mx = metaX[j], my = metaY[j];
        int y1 = my & 0xffff, y2 = my >> 16;
        int lo = max(y1, y0), hi = min(y2, y0 + BAND);
        float acc = 0.f;
        if (lo < hi) {
            int x1 = mx & 0xffff, x2m1 = mx >> 16;
            const float* Pp = P + (lo - y0) * PSTR;
            if (x1 > 0) {
                for (int r = lo; r < hi; ++r, Pp += PSTR) acc += Pp[x2m1] - Pp[x1 - 1];
            } else {
                for (int r = lo; r < hi; ++r, Pp += PSTR) acc += Pp[x2m1];
            }
        }
        outp[j] = acc;
    }
}

// ---------------------------------------------------------------------------
// K2: blocks 0..18 finalize det term (sum 48 band partials, fixed order);
//     blocks 19..34 do plate IoU + OCR for batch b = blk-19.
// ---------------------------------------------------------------------------
__global__ __launch_bounds__(256) void k_small(const float* __restrict__ det_boxes,
                                               const float* __restrict__ logits,
                                               const float* __restrict__ plate_boxes,
                                               const float* __restrict__ plate_conf,
                                               const float* __restrict__ ocr,
                                               const float* __restrict__ detPartial,
                                               float* __restrict__ detPart,
                                               float* __restrict__ platePart,
                                               float* __restrict__ plateCnt,
                                               float* __restrict__ ocrPart) {
    const int t = threadIdx.x;
    if (blockIdx.x < NDETBLK) {
        const int idx = blockIdx.x * 256 + t;
        float contrib = 0.f;
        if (idx < BB * NN) {
            const int b = idx / NN, j = idx % NN;
            const float* lg = logits + (size_t)idx * 7;
            float m = lg[0];
            #pragma unroll
            for (int i = 1; i < 7; ++i) m = fmaxf(m, lg[i]);
            float ssum = 0.f;
            #pragma unroll
            for (int i = 0; i < 7; ++i) ssum += expf(lg[i] - m);
            float conf = 1.f / ssum;

            const float* bxp = det_boxes + (size_t)idx * 4;
            float cx = bxp[0], cy = bxp[1], w = bxp[2], h = bxp[3];
            int x1 = (int)floorf((cx - w * 0.5f) * (float)WW);
            int y1 = (int)floorf((cy - h * 0.5f) * (float)HH);
            int x2 = (int)floorf((cx + w * 0.5f) * (float)WW);
            int y2 = (int)floorf((cy + h * 0.5f) * (float)HH);
            x1 = min(max(x1, 0), WW - 1); y1 = min(max(y1, 0), HH - 1);
            x2 = min(max(x2, 0), WW - 1); y2 = min(max(y2, 0), HH - 1);
            if (conf >= 0.3f && x2 > x1 && y2 > y1) {
                const float* pp = detPartial + (size_t)b * NBAND * NN + j;
                float Sb = 0.f;
                #pragma unroll
                for (int g2 = 0; g2 < NBAND; ++g2) Sb += pp[(size_t)g2 * NN];
                float area = (float)((y2 - y1) * (x2 - x1));
                contrib = relu_f(Sb / area) * conf;
            }
        }
        __shared__ float red[256];
        red[t] = contrib;
        __syncthreads();
        for (int k = 128; k > 0; k >>= 1) {
            if (t < k) red[t] += red[t + k];
            __syncthreads();
        }
        if (t == 0) detPart[blockIdx.x] = red[0];
    } else {
        const float CONF_TH = 0.3f, MIN_IOU = 0.5f, OCR_TH = 0.7f;
        const int b = blockIdx.x - NDETBLK;

        __shared__ float vx1[NN], vy1[NN], vx2[NN], vy2[NN], va[NN], vcf[NN];
        __shared__ int anyv;
        __shared__ float redf[256];
        __shared__ int   redi[256];

        if (t == 0) anyv = 0;
        __syncthreads();

        for (int j = t; j < NN; j += 256) {
            const float* bxp = det_boxes + ((size_t)b * NN + j) * 4;
            float cx = bxp[0], cy = bxp[1], w = bxp[2], h = bxp[3];
            float x1 = cx - w * 0.5f, y1 = cy - h * 0.5f;
            float x2 = cx + w * 0.5f, y2 = cy + h * 0.5f;
            vx1[j] = x1; vy1[j] = y1; vx2[j] = x2; vy2[j] = y2;
            va[j] = (x2 - x1) * (y2 - y1);
            const float* lg = logits + ((size_t)b * NN + j) * 7;
            float m = lg[0];
            #pragma unroll
            for (int i = 1; i < 7; ++i) m = fmaxf(m, lg[i]);
            float sum = 0.f;
            #pragma unroll
            for (int i = 0; i < 7; ++i) sum += expf(lg[i] - m);
            float cc = 1.f / sum;
            vcf[j] = cc;
            if (cc > CONF_TH) atomicOr(&anyv, 1);
        }
        __syncthreads();

        float term = 0.f; int pv = 0; float pcf = -1e30f;
        if (t < PP) {
            const float* bxp = plate_boxes + ((size_t)b * PP + t) * 4;
            float cx = bxp[0], cy = bxp[1], w = bxp[2], h = bxp[3];
            float px1 = cx - w * 0.5f, py1 = cy - h * 0.5f;
            float px2 = cx + w * 0.5f, py2 = cy + h * 0.5f;
            float a1 = (px2 - px1) * (py2 - py1);
            pcf = plate_conf[b * PP + t];
            pv = (pcf > CONF_TH) ? 1 : 0;
            float max_iou = -1.f;
            for (int j = 0; j < NN; ++j) {
                if (vcf[j] > CONF_TH) {
                    float ltx = fmaxf(px1, vx1[j]);
                    float lty = fmaxf(py1, vy1[j]);
                    float rbx = fminf(px2, vx2[j]);
                    float rby = fminf(py2, vy2[j]);
                    float iw = fmaxf(rbx - ltx, 0.f);
                    float ih = fmaxf(rby - lty, 0.f);
                    float inter = iw * ih;
                    float uni = a1 + va[j] - inter;
                    float iou = inter / (uni + 1e-8f);
                    max_iou = fmaxf(max_iou, iou);
                }
            }
            if (pv) term = relu_f(MIN_IOU - max_iou) * pcf;
        }

        redf[t] = term; redi[t] = pv;
        __syncthreads();
        for (int k = 128; k > 0; k >>= 1) {
            if (t < k) { redf[t] += redf[t + k]; redi[t] += redi[t + k]; }
            __syncthreads();
        }
        float termsum = redf[0];
        int   cnt     = redi[0];
        __syncthreads();

        float osum = 0.f;
        if (t < LL) {
            const float* op = ocr + ((size_t)b * LL + t) * 37;
            float m = op[0];
            #pragma unroll
            for (int i = 1; i < 37; ++i) m = fmaxf(m, op[i]);
            osum = m;
        }
        redf[t] = osum;
        __syncthreads();
        for (int k = 128; k > 0; k >>= 1) {
            if (t < k) redf[t] += redf[t + k];
            __syncthreads();
        }
        float avg_ocr = redf[0] / (float)LL;
        __syncthreads();

        redf[t] = (t < PP) ? pcf : -1e30f;
        __syncthreads();
        for (int k = 128; k > 0; k >>= 1) {
            if (t < k) redf[t] = fmaxf(redf[t], redf[t + k]);
            __syncthreads();
        }
        float max_plate = redf[0];

        if (t == 0) {
            platePart[b] = (cnt > 0 && anyv) ? termsum : 0.f;
            plateCnt[b]  = (float)cnt;
            ocrPart[b]   = (avg_ocr > OCR_TH) ? relu_f(avg_ocr - max_plate) : 0.f;
        }
    }
}

// ---------------------------------------------------------------------------
// K3: final deterministic combine.
// ---------------------------------------------------------------------------
__global__ __launch_bounds__(64) void k_final(const float* __restrict__ detPart,
                                              const float* __restrict__ platePart,
                                              const float* __restrict__ plateCnt,
                                              const float* __restrict__ ocrPart,
                                              float* __restrict__ out) {
    if (threadIdx.x == 0 && blockIdx.x == 0) {
        double ds = 0.0;
        for (int i = 0; i < NDETBLK; ++i) ds += (double)detPart[i];
        double ps = 0.0, cnt = 0.0, os = 0.0;
        for (int b = 0; b < BB; ++b) {
            ps  += (double)platePart[b];
            cnt += (double)plateCnt[b];
            os  += (double)ocrPart[b];
        }
        float det_seg   = (float)ds / (float)(BB * NN);
        float plate_det = (float)ps / fmaxf((float)cnt, 1.f);
        float ocr_plate = (float)os / (float)BB;
        out[0] = 0.1f * det_seg + 0.1f * plate_det + 0.1f * ocr_plate;
    }
}

extern "C" void kernel_launch(void* const* d_in, const int* in_sizes, int n_in,
                              void* d_out, int out_size, void* d_ws, size_t ws_size,
                              hipStream_t stream) {
    const float* det_boxes   = (const float*)d_in[0];
    const float* det_logits  = (const float*)d_in[1];
    const float* seg_masks   = (const float*)d_in[2];
    const float* plate_boxes = (const float*)d_in[3];
    const float* plate_conf  = (const float*)d_in[4];
    const float* ocr_probs   = (const float*)d_in[5];
    float* out = (float*)d_out;

    // workspace layout (floats)
    float* detPartial = (float*)d_ws;                          // B*NBAND*N = 230400
    float* detPart    = detPartial + (size_t)BB * NBAND * NN;  // 19
    float* platePart  = detPart + NDETBLK;                     // 16
    float* plateCnt   = platePart + BB;                        // 16
    float* ocrPart    = plateCnt + BB;                         // 16

    k_band<<<BB * NBAND, 512, 0, stream>>>(seg_masks, det_boxes, det_logits,
                                           detPartial);
    k_small<<<NDETBLK + BB, 256, 0, stream>>>(det_boxes, det_logits, plate_boxes,
                                              plate_conf, ocr_probs, detPartial,
                                              detPart, platePart, plateCnt, ocrPart);
    k_final<<<1, 64, 0, stream>>>(detPart, platePart, plateCnt, ocrPart, out);
}